// Round 8
// baseline (603.835 us; speedup 1.0000x reference)
//
#include <hip/hip_runtime.h>
#include <hip/hip_bf16.h>
#include <stdint.h>

#define N      2048
#define NHEADS 8
#define ALPHA  0.2f
#define NW     (N / 64)   // 32 bitmask words per row
#define NB     512        // grid size; co-resident: __launch_bounds__(256,2) => 2 blocks/CU x 256 CU

typedef __attribute__((ext_vector_type(8))) short bf16x8;
typedef __attribute__((ext_vector_type(4))) float f32x4;
typedef unsigned long long u64;

__device__ __forceinline__ short f2bf(float f) {
    union { float f; unsigned u; } v; v.f = f;
    unsigned r = v.u + 0x7fffu + ((v.u >> 16) & 1u);   // RNE
    return (short)(r >> 16);
}
__device__ __forceinline__ unsigned pack2(float a, float b) {
    return (unsigned)(unsigned short)f2bf(a) | ((unsigned)(unsigned short)f2bf(b) << 16);
}

struct MegaParams {
    const int* adj; const float* x; const float* W; const float* Wf;
    const float* a1; const float* a2; const float* a1f; const float* a2f;
    unsigned* bar;                       // 5 single-use barrier slots (zeroed per call)
    u64* bits; short* xb; short* Wtb; short* Wftb;
    short* Htb; short* x2b; short* H2tb;
    float* s1; float* s2; float* s1f; float* s2f;
    float* pout; float* psum; float* out;
};

// smem (floats): [0,4224) redC[2][32][66] / prep tile[64][65](4160); [4224,4288) redS[2][32];
// [4288,4320) emaxL[32]
#define SMEM_FLOATS 4320

// ---------------------------------------------------------------- device-scope grid barrier
// Each slot used exactly once per launch; slots pre-zeroed by hipMemsetAsync each call.
__device__ __forceinline__ void gsync(unsigned* slot) {
    __syncthreads();                                   // drains this block's vmcnt (HW barrier semantics)
    if (threadIdx.x == 0) {
        __threadfence();                               // agent-scope release (L2 writeback)
        __hip_atomic_fetch_add(slot, 1u, __ATOMIC_ACQ_REL, __HIP_MEMORY_SCOPE_AGENT);
        while (__hip_atomic_load(slot, __ATOMIC_ACQUIRE, __HIP_MEMORY_SCOPE_AGENT) < NB)
            __builtin_amdgcn_s_sleep(1);
        __threadfence();                               // agent-scope acquire (L2 invalidate)
    }
    __syncthreads();
}

// ---------------------------------------------------------------- P1: prep (r6-proven body)
__device__ void phase_prep(const MegaParams& P, float* smem) {
    const int bid = blockIdx.x, t = threadIdx.x;
    for (int vb = bid; vb < 584; vb += NB) {
        if (vb < 256) {
            int wave = t >> 6, lane = t & 63;
            #pragma unroll
            for (int rr = 0; rr < 8; ++rr) {
                int i = vb * 8 + rr;
                for (int w = wave; w < NW; w += 4) {
                    u64 m = __ballot(P.adj[(size_t)i * N + w * 64 + lane] > 0);
                    if (lane == 0) P.bits[(size_t)i * NW + w] = m;
                }
            }
        } else if (vb < 512) {
            int base = (vb - 256) * 512 + t;
            #pragma unroll
            for (int q = 0; q < 2; ++q) {
                int idx = base + q * 256;
                const float4 a = ((const float4*)P.x)[idx * 2];
                const float4 c = ((const float4*)P.x)[idx * 2 + 1];
                ((uint4*)P.xb)[idx] = make_uint4(pack2(a.x, a.y), pack2(a.z, a.w),
                                                 pack2(c.x, c.y), pack2(c.z, c.w));
            }
        } else {
            float (*tile)[65] = (float(*)[65])smem;
            const float* src_base; short* dst_base; int r0;
            if (vb < 576) {
                int idx = vb - 512;
                int h = idx >> 3; r0 = (idx & 7) * 64;
                src_base = P.W + (size_t)h * 512 * 64;
                dst_base = P.Wtb + (size_t)h * 64 * 512;
            } else {
                int idx = vb - 576; r0 = idx * 64;
                src_base = P.Wf; dst_base = P.Wftb;
            }
            {
                int r = t >> 2, cq = (t & 3) * 16;
                const float* src = src_base + (size_t)(r0 + r) * 64 + cq;
                #pragma unroll
                for (int q = 0; q < 4; ++q) {
                    float4 v = ((const float4*)src)[q];
                    tile[r][cq + q * 4 + 0] = v.x; tile[r][cq + q * 4 + 1] = v.y;
                    tile[r][cq + q * 4 + 2] = v.z; tile[r][cq + q * 4 + 3] = v.w;
                }
            }
            __syncthreads();
            {
                int c = t >> 2, rq = (t & 3) * 16;
                unsigned u[8];
                #pragma unroll
                for (int p = 0; p < 8; ++p)
                    u[p] = pack2(tile[rq + 2 * p][c], tile[rq + 2 * p + 1][c]);
                short* dst = dst_base + (size_t)c * 512 + r0 + rq;
                ((uint4*)dst)[0] = make_uint4(u[0], u[1], u[2], u[3]);
                ((uint4*)dst)[1] = make_uint4(u[4], u[5], u[6], u[7]);
            }
        }
    }
}

// ---------------------------------------------------------------- gemm + fused scores (r2-proven + r3/r4-exonerated epilogue)
template <int RT>
__device__ void phase_gemm(const short* __restrict__ Ab, const short* __restrict__ Btb,
                           short* __restrict__ Ctb,
                           const float* __restrict__ a1, const float* __restrict__ a2,
                           float* __restrict__ s1, float* __restrict__ s2,
                           int M, int K, int nbx, int vbid) {
    const int t = threadIdx.x, wave = t >> 6, lane = t & 63;
    const int c = lane & 15, g = lane >> 4;
    const int h = vbid / nbx, bx = vbid % nbx;
    const int i0 = bx * (4 * RT * 16) + wave * (RT * 16);
    const short* Bh = Btb + (size_t)h * 64 * K;
    f32x4 acc[RT][4];
    #pragma unroll
    for (int rt = 0; rt < RT; ++rt)
        #pragma unroll
        for (int dt = 0; dt < 4; ++dt) { acc[rt][dt][0]=0.f; acc[rt][dt][1]=0.f; acc[rt][dt][2]=0.f; acc[rt][dt][3]=0.f; }
    for (int k0 = 0; k0 < K; k0 += 32) {
        bf16x8 af[RT];
        #pragma unroll
        for (int rt = 0; rt < RT; ++rt)
            af[rt] = *(const bf16x8*)(Ab + (size_t)(i0 + rt * 16 + c) * K + k0 + g * 8);
        #pragma unroll
        for (int dt = 0; dt < 4; ++dt) {
            bf16x8 bf = *(const bf16x8*)(Bh + (size_t)(dt * 16 + c) * K + k0 + g * 8);
            #pragma unroll
            for (int rt = 0; rt < RT; ++rt)
                acc[rt][dt] = __builtin_amdgcn_mfma_f32_16x16x32_bf16(af[rt], bf, acc[rt][dt], 0, 0, 0);
        }
    }
    #pragma unroll
    for (int rt = 0; rt < RT; ++rt)
        #pragma unroll
        for (int dt = 0; dt < 4; ++dt) {
            int n = dt * 16 + c;
            int i = i0 + rt * 16 + g * 4;
            uint2 u = make_uint2(pack2(acc[rt][dt][0], acc[rt][dt][1]),
                                 pack2(acc[rt][dt][2], acc[rt][dt][3]));
            *(uint2*)(Ctb + (size_t)(h * 64 + n) * M + i) = u;
        }
    float a1v[4], a2v[4];
    #pragma unroll
    for (int dt = 0; dt < 4; ++dt) {
        a1v[dt] = a1[h * 64 + dt * 16 + c];
        a2v[dt] = a2[h * 64 + dt * 16 + c];
    }
    #pragma unroll
    for (int rt = 0; rt < RT; ++rt)
        #pragma unroll
        for (int r = 0; r < 4; ++r) {
            float p1 = 0.f, p2 = 0.f;
            #pragma unroll
            for (int dt = 0; dt < 4; ++dt) {
                p1 += acc[rt][dt][r] * a1v[dt];
                p2 += acc[rt][dt][r] * a2v[dt];
            }
            #pragma unroll
            for (int off = 1; off < 16; off <<= 1) {
                p1 += __shfl_xor(p1, off);
                p2 += __shfl_xor(p2, off);
            }
            if (c == 0) {
                int i = i0 + rt * 16 + g * 4 + r;
                s1[(size_t)h * N + i] = p1;
                s2[(size_t)h * N + i] = p2;
            }
        }
}

// ---------------------------------------------------------------- attn: in-block emax + PV + 2-stage reduce
// MODE 0: outB bf16 [i][h*64+d] = elu(att@H); MODE 1: outF f32 partials + psum (z-split).
template <int RT, int MODE>
__device__ void phase_attn(const u64* __restrict__ bits,
                           const float* __restrict__ s1h, const float* __restrict__ s2h,
                           const short* __restrict__ Htb,
                           short* __restrict__ outB, float* __restrict__ outF,
                           float* __restrict__ psum,
                           int h, int i0, int z, int zchunks, float* smem) {
    const int t = threadIdx.x, wave = t >> 6, lane = t & 63;
    const int c = lane & 15, g = lane >> 4;
    const int ROWS = RT * 16;
    float* redC  = smem;               // [2][ROWS][66]
    float* redS  = smem + 4224;        // [2][32] (ROWS-strided)
    float* emaxL = smem + 4288;        // [32]
    const float* s1 = s1h + (size_t)h * N;

    // in-block masked row max over FULL row (rowmax_k semantics, r2-proven)
    for (int r = wave; r < ROWS; r += 4) {
        int i = i0 + r;
        u64 word = bits[(size_t)i * NW + (lane >> 1)];
        unsigned hw = (lane & 1) ? (unsigned)(word >> 32) : (unsigned)word;
        int jj = lane * 32;
        float mx = -3e38f;
        #pragma unroll
        for (int q = 0; q < 8; ++q) {
            float4 v = *(const float4*)(s1 + jj + q * 4);
            if ((hw >> (q * 4 + 0)) & 1) mx = fmaxf(mx, v.x);
            if ((hw >> (q * 4 + 1)) & 1) mx = fmaxf(mx, v.y);
            if ((hw >> (q * 4 + 2)) & 1) mx = fmaxf(mx, v.z);
            if ((hw >> (q * 4 + 3)) & 1) mx = fmaxf(mx, v.w);
        }
        #pragma unroll
        for (int off = 32; off; off >>= 1) mx = fmaxf(mx, __shfl_xor(mx, off));
        if (lane == 0) {
            float e = mx + s2h[(size_t)h * N + i];
            emaxL[r] = fmaxf(e, ALPHA * e);
        }
    }
    __syncthreads();

    const u64* brow[RT];
    float s2v[RT], emv[RT];
    #pragma unroll
    for (int rt = 0; rt < RT; ++rt) {
        int i = i0 + rt * 16 + c;
        brow[rt] = bits + (size_t)i * NW;
        s2v[rt] = s2h[(size_t)h * N + i];
        emv[rt] = emaxL[rt * 16 + c];
    }

    f32x4 acc[RT][4];
    #pragma unroll
    for (int rt = 0; rt < RT; ++rt)
        #pragma unroll
        for (int dt = 0; dt < 4; ++dt) { acc[rt][dt][0]=0.f; acc[rt][dt][1]=0.f; acc[rt][dt][2]=0.f; acc[rt][dt][3]=0.f; }
    float wsum[RT];
    #pragma unroll
    for (int rt = 0; rt < RT; ++rt) wsum[rt] = 0.f;

    for (int cc = wave; cc < zchunks; cc += 4) {        // r2-proven j-loop
        const int j0 = (z * zchunks + cc) * 32;
        const int wi = j0 >> 6;
        const int sh = (j0 & 32) + g * 8;
        const float4 q0 = *(const float4*)(s1 + j0 + g * 8);
        const float4 q1 = *(const float4*)(s1 + j0 + g * 8 + 4);
        const float s1e[8] = {q0.x, q0.y, q0.z, q0.w, q1.x, q1.y, q1.z, q1.w};
        bf16x8 af[RT];
        #pragma unroll
        for (int rt = 0; rt < RT; ++rt) {
            unsigned byte = (unsigned)(brow[rt][wi] >> sh) & 0xffu;
            #pragma unroll
            for (int e = 0; e < 8; ++e) {
                float ev = s1e[e] + s2v[rt];
                ev = fmaxf(ev, ALPHA * ev);                       // LeakyReLU
                float w = ((byte >> e) & 1u) ? __expf(ev - emv[rt]) : 0.f;
                wsum[rt] += w;
                af[rt][e] = f2bf(w);
            }
        }
        #pragma unroll
        for (int dt = 0; dt < 4; ++dt) {
            bf16x8 bf = *(const bf16x8*)(Htb + (size_t)(h * 64 + dt * 16 + c) * N + j0 + g * 8);
            #pragma unroll
            for (int rt = 0; rt < RT; ++rt)
                acc[rt][dt] = __builtin_amdgcn_mfma_f32_16x16x32_bf16(af[rt], bf, acc[rt][dt], 0, 0, 0);
        }
    }

    #pragma unroll
    for (int rt = 0; rt < RT; ++rt) {
        wsum[rt] += __shfl_xor(wsum[rt], 16);
        wsum[rt] += __shfl_xor(wsum[rt], 32);
    }

    // 2-stage pairwise cross-wave reduce (halves LDS vs 1-stage [4][..])
    if (wave >= 2) {
        int hf = wave - 2;
        #pragma unroll
        for (int rt = 0; rt < RT; ++rt) {
            #pragma unroll
            for (int dt = 0; dt < 4; ++dt)
                #pragma unroll
                for (int r = 0; r < 4; ++r)
                    redC[(size_t)hf * ROWS * 66 + (rt * 16 + g * 4 + r) * 66 + dt * 16 + c] = acc[rt][dt][r];
            if (g == 0) redS[hf * ROWS + rt * 16 + c] = wsum[rt];
        }
    }
    __syncthreads();
    if (wave < 2) {
        #pragma unroll
        for (int rt = 0; rt < RT; ++rt) {
            #pragma unroll
            for (int dt = 0; dt < 4; ++dt)
                #pragma unroll
                for (int r = 0; r < 4; ++r)
                    acc[rt][dt][r] += redC[(size_t)wave * ROWS * 66 + (rt * 16 + g * 4 + r) * 66 + dt * 16 + c];
            wsum[rt] += redS[wave * ROWS + rt * 16 + c];
        }
    }
    __syncthreads();
    if (wave == 1) {
        #pragma unroll
        for (int rt = 0; rt < RT; ++rt) {
            #pragma unroll
            for (int dt = 0; dt < 4; ++dt)
                #pragma unroll
                for (int r = 0; r < 4; ++r)
                    redC[(rt * 16 + g * 4 + r) * 66 + dt * 16 + c] = acc[rt][dt][r];
            if (g == 0) redS[rt * 16 + c] = wsum[rt];
        }
    }
    __syncthreads();
    if (wave == 0) {
        #pragma unroll
        for (int rt = 0; rt < RT; ++rt) {
            #pragma unroll
            for (int dt = 0; dt < 4; ++dt)
                #pragma unroll
                for (int r = 0; r < 4; ++r)
                    acc[rt][dt][r] += redC[(rt * 16 + g * 4 + r) * 66 + dt * 16 + c];
            wsum[rt] += redS[rt * 16 + c];
        }
        // writeback (wave 0 holds full sums; row sums gathered via shfl: wsum[rt] lives at lane c=row&15)
        #pragma unroll
        for (int rt = 0; rt < RT; ++rt)
            #pragma unroll
            for (int r = 0; r < 4; ++r) {
                float ws = __shfl(wsum[rt], g * 4 + r);
                int row = rt * 16 + g * 4 + r;
                #pragma unroll
                for (int dt = 0; dt < 4; ++dt) {
                    if (MODE == 0) {
                        float v = acc[rt][dt][r] / ws;
                        v = v > 0.f ? v : (__expf(v) - 1.f);      // fused elu
                        outB[(size_t)(i0 + row) * (NHEADS * 64) + h * 64 + dt * 16 + c] = f2bf(v);
                    } else {
                        outF[((size_t)z * N + i0 + row) * 64 + dt * 16 + c] = acc[rt][dt][r];
                    }
                }
            }
        if (MODE == 1 && g == 0) {
            #pragma unroll
            for (int rt = 0; rt < RT; ++rt)
                psum[(size_t)z * N + i0 + rt * 16 + c] = wsum[rt];
        }
    }
}

// ---------------------------------------------------------------- the mega kernel (6 phases, 5 barriers)
__global__ __launch_bounds__(256, 2) void mega(MegaParams P) {
    __shared__ float smem[SMEM_FLOATS];
    const int bid = blockIdx.x;

    phase_prep(P, smem);
    gsync(P.bar + 0);
    if ((bid & 3) == 0)     // 128 virtual blocks spread across CUs
        phase_gemm<2>(P.xb, P.Wtb, P.Htb, P.a1, P.a2, P.s1, P.s2, N, 512, 16, bid >> 2);
    gsync(P.bar + 1);
    // layer-1 attn: 64 i-tiles x 8 heads = 512 blocks, 32 rows each
    phase_attn<2, 0>(P.bits, P.s1, P.s2, P.Htb, P.x2b, nullptr, nullptr,
                     bid >> 6, (bid & 63) * 32, 0, 64, smem);
    gsync(P.bar + 2);
    if ((bid & 31) == 0)    // 16 virtual blocks
        phase_gemm<2>(P.x2b, P.Wftb, P.H2tb, P.a1f, P.a2f, P.s1f, P.s2f, N, 512, 16, bid >> 5);
    gsync(P.bar + 3);
    // layer-2 attn: 128 i-tiles x 4 z = 512 blocks, 16 rows, unnormalized partials
    phase_attn<1, 1>(P.bits, P.s1f, P.s2f, P.H2tb, nullptr, P.pout, P.psum,
                     0, (bid >> 2) * 16, bid & 3, 16, smem);
    gsync(P.bar + 4);
    {   // combine 4 z-partials (r1-proven pattern)
        int idx = bid * 256 + threadIdx.x;   // N*64 = 512*256
        int i = idx >> 6;
        float a = 0.f, s = 0.f;
        #pragma unroll
        for (int zz = 0; zz < 4; ++zz) {
            a += P.pout[(size_t)zz * N * 64 + idx];
            s += P.psum[(size_t)zz * N + i];
        }
        P.out[idx] = a / s;
    }
}

// ---------------------------------------------------------------- launch: memset(barrier) + 1 kernel
extern "C" void kernel_launch(void* const* d_in, const int* in_sizes, int n_in,
                              void* d_out, int out_size, void* d_ws, size_t ws_size,
                              hipStream_t stream) {
    char* ws = (char*)d_ws;
    MegaParams P;
    P.x   = (const float*)d_in[0];
    P.adj = (const int*)d_in[1];
    P.W   = (const float*)d_in[2];
    P.a1  = (const float*)d_in[3];
    P.a2  = (const float*)d_in[4];
    P.Wf  = (const float*)d_in[5];
    P.a1f = (const float*)d_in[6];
    P.a2f = (const float*)d_in[7];
    P.out = (float*)d_out;

    P.bar  = (unsigned*)ws; ws += 64;                           // 5 slots (+pad)
    P.bits = (u64*)ws;   ws += (size_t)N * NW * 8;              // 512 KB
    P.xb   = (short*)ws; ws += (size_t)N * 512 * 2;             // 2 MB
    P.Wtb  = (short*)ws; ws += (size_t)8 * 64 * 512 * 2;        // 512 KB
    P.Wftb = (short*)ws; ws += (size_t)64 * 512 * 2;            // 64 KB
    P.Htb  = (short*)ws; ws += (size_t)512 * N * 2;             // 2 MB
    P.x2b  = (short*)ws; ws += (size_t)N * 512 * 2;             // 2 MB
    P.H2tb = (short*)ws; ws += (size_t)64 * N * 2;              // 256 KB
    P.s1   = (float*)ws; ws += (size_t)NHEADS * N * 4;
    P.s2   = (float*)ws; ws += (size_t)NHEADS * N * 4;
    P.s1f  = (float*)ws; ws += (size_t)N * 4;
    P.s2f  = (float*)ws; ws += (size_t)N * 4;
    P.pout = (float*)ws; ws += (size_t)4 * N * 64 * 4;          // 2 MB
    P.psum = (float*)ws; ws += (size_t)4 * N * 4;

    hipMemsetAsync(P.bar, 0, 64, stream);                       // zero barrier slots (capturable)
    mega<<<dim3(NB), dim3(256), 0, stream>>>(P);
}

// Round 10
// 230.953 us; speedup vs baseline: 2.6145x; 2.6145x over previous
//
#include <hip/hip_runtime.h>
#include <hip/hip_bf16.h>
#include <stdint.h>

#define N      2048
#define NHEADS 8
#define ALPHA  0.2f
#define NW     (N / 64)   // 32 bitmask words per row
#define NB     512        // grid size; co-resident: __launch_bounds__(256,2) => 2 blocks/CU x 256 CU
#define BAR_STRIDE 1024   // uints per barrier slot (level-0 counters 128B apart + root)

typedef __attribute__((ext_vector_type(8))) short bf16x8;
typedef __attribute__((ext_vector_type(4))) float f32x4;
typedef unsigned long long u64;

__device__ __forceinline__ short f2bf(float f) {
    union { float f; unsigned u; } v; v.f = f;
    unsigned r = v.u + 0x7fffu + ((v.u >> 16) & 1u);   // RNE
    return (short)(r >> 16);
}
__device__ __forceinline__ unsigned pack2(float a, float b) {
    return (unsigned)(unsigned short)f2bf(a) | ((unsigned)(unsigned short)f2bf(b) << 16);
}

struct MegaParams {
    const int* adj; const float* x; const float* W; const float* Wf;
    const float* a1; const float* a2; const float* a1f; const float* a2f;
    unsigned* bar;                       // 5 barrier slots x BAR_STRIDE uints, zeroed per call
    u64* bits; short* xb; short* Wtb; short* Wftb;
    short* Htb; short* x2b; short* H2tb;
    float* s1; float* s2; float* s1f; float* s2f;
    float* pout; float* psum; float* out;
};

// smem (floats): [0,4224) redC[2][32][66] / prep tile[64][65](4160); [4224,4288) redS[2][32];
// [4288,4320) emaxL[32]
#define SMEM_FLOATS 4320

// ---------------------------------------------------------------- device-scope grid barrier
// r8 bug: ACQUIRE polling emitted buffer_inv per iteration -> L2 invalidate storm (~120us/barrier).
// Fix: tree arrival (8 spaced L0 counters -> root), RELAXED polling, ONE acquire load at exit
// (single buffer_inv; __hip_atomic_fence does not exist in these headers — r9 compile fail).
__device__ __forceinline__ void gsync(unsigned* base) {
    __syncthreads();                                   // all block's prior mem ops drained (vmcnt0)
    if (threadIdx.x == 0) {
        unsigned* l0   = base + (blockIdx.x & 7) * 32; // 128B-spaced level-0 counters
        unsigned* root = base + 8 * 32;
        // release: publish this block's writes (wbl2), then arrive
        unsigned old = __hip_atomic_fetch_add(l0, 1u, __ATOMIC_ACQ_REL, __HIP_MEMORY_SCOPE_AGENT);
        if (old == (NB / 8 - 1))                       // last arriver of this group
            __hip_atomic_fetch_add(root, 1u, __ATOMIC_ACQ_REL, __HIP_MEMORY_SCOPE_AGENT);
        // relaxed spin: agent-scope load sees remote updates, NO buffer_inv per poll
        while (__hip_atomic_load(root, __ATOMIC_RELAXED, __HIP_MEMORY_SCOPE_AGENT) < 8u)
            __builtin_amdgcn_s_sleep(2);
        // single acquire load: one-time L2 invalidate before consuming other XCDs' data
        (void)__hip_atomic_load(root, __ATOMIC_ACQUIRE, __HIP_MEMORY_SCOPE_AGENT);
    }
    __syncthreads();
}

// ---------------------------------------------------------------- P1: prep (r8-proven body, verbatim)
__device__ void phase_prep(const MegaParams& P, float* smem) {
    const int bid = blockIdx.x, t = threadIdx.x;
    for (int vb = bid; vb < 584; vb += NB) {
        if (vb < 256) {
            int wave = t >> 6, lane = t & 63;
            #pragma unroll
            for (int rr = 0; rr < 8; ++rr) {
                int i = vb * 8 + rr;
                for (int w = wave; w < NW; w += 4) {
                    u64 m = __ballot(P.adj[(size_t)i * N + w * 64 + lane] > 0);
                    if (lane == 0) P.bits[(size_t)i * NW + w] = m;
                }
            }
        } else if (vb < 512) {
            int base = (vb - 256) * 512 + t;
            #pragma unroll
            for (int q = 0; q < 2; ++q) {
                int idx = base + q * 256;
                const float4 a = ((const float4*)P.x)[idx * 2];
                const float4 c = ((const float4*)P.x)[idx * 2 + 1];
                ((uint4*)P.xb)[idx] = make_uint4(pack2(a.x, a.y), pack2(a.z, a.w),
                                                 pack2(c.x, c.y), pack2(c.z, c.w));
            }
        } else {
            float (*tile)[65] = (float(*)[65])smem;
            const float* src_base; short* dst_base; int r0;
            if (vb < 576) {
                int idx = vb - 512;
                int h = idx >> 3; r0 = (idx & 7) * 64;
                src_base = P.W + (size_t)h * 512 * 64;
                dst_base = P.Wtb + (size_t)h * 64 * 512;
            } else {
                int idx = vb - 576; r0 = idx * 64;
                src_base = P.Wf; dst_base = P.Wftb;
            }
            {
                int r = t >> 2, cq = (t & 3) * 16;
                const float* src = src_base + (size_t)(r0 + r) * 64 + cq;
                #pragma unroll
                for (int q = 0; q < 4; ++q) {
                    float4 v = ((const float4*)src)[q];
                    tile[r][cq + q * 4 + 0] = v.x; tile[r][cq + q * 4 + 1] = v.y;
                    tile[r][cq + q * 4 + 2] = v.z; tile[r][cq + q * 4 + 3] = v.w;
                }
            }
            __syncthreads();
            {
                int c = t >> 2, rq = (t & 3) * 16;
                unsigned u[8];
                #pragma unroll
                for (int p = 0; p < 8; ++p)
                    u[p] = pack2(tile[rq + 2 * p][c], tile[rq + 2 * p + 1][c]);
                short* dst = dst_base + (size_t)c * 512 + r0 + rq;
                ((uint4*)dst)[0] = make_uint4(u[0], u[1], u[2], u[3]);
                ((uint4*)dst)[1] = make_uint4(u[4], u[5], u[6], u[7]);
            }
        }
    }
}

// ---------------------------------------------------------------- gemm + fused scores (r8-proven, verbatim)
template <int RT>
__device__ void phase_gemm(const short* __restrict__ Ab, const short* __restrict__ Btb,
                           short* __restrict__ Ctb,
                           const float* __restrict__ a1, const float* __restrict__ a2,
                           float* __restrict__ s1, float* __restrict__ s2,
                           int M, int K, int nbx, int vbid) {
    const int t = threadIdx.x, wave = t >> 6, lane = t & 63;
    const int c = lane & 15, g = lane >> 4;
    const int h = vbid / nbx, bx = vbid % nbx;
    const int i0 = bx * (4 * RT * 16) + wave * (RT * 16);
    const short* Bh = Btb + (size_t)h * 64 * K;
    f32x4 acc[RT][4];
    #pragma unroll
    for (int rt = 0; rt < RT; ++rt)
        #pragma unroll
        for (int dt = 0; dt < 4; ++dt) { acc[rt][dt][0]=0.f; acc[rt][dt][1]=0.f; acc[rt][dt][2]=0.f; acc[rt][dt][3]=0.f; }
    for (int k0 = 0; k0 < K; k0 += 32) {
        bf16x8 af[RT];
        #pragma unroll
        for (int rt = 0; rt < RT; ++rt)
            af[rt] = *(const bf16x8*)(Ab + (size_t)(i0 + rt * 16 + c) * K + k0 + g * 8);
        #pragma unroll
        for (int dt = 0; dt < 4; ++dt) {
            bf16x8 bf = *(const bf16x8*)(Bh + (size_t)(dt * 16 + c) * K + k0 + g * 8);
            #pragma unroll
            for (int rt = 0; rt < RT; ++rt)
                acc[rt][dt] = __builtin_amdgcn_mfma_f32_16x16x32_bf16(af[rt], bf, acc[rt][dt], 0, 0, 0);
        }
    }
    #pragma unroll
    for (int rt = 0; rt < RT; ++rt)
        #pragma unroll
        for (int dt = 0; dt < 4; ++dt) {
            int n = dt * 16 + c;
            int i = i0 + rt * 16 + g * 4;
            uint2 u = make_uint2(pack2(acc[rt][dt][0], acc[rt][dt][1]),
                                 pack2(acc[rt][dt][2], acc[rt][dt][3]));
            *(uint2*)(Ctb + (size_t)(h * 64 + n) * M + i) = u;
        }
    float a1v[4], a2v[4];
    #pragma unroll
    for (int dt = 0; dt < 4; ++dt) {
        a1v[dt] = a1[h * 64 + dt * 16 + c];
        a2v[dt] = a2[h * 64 + dt * 16 + c];
    }
    #pragma unroll
    for (int rt = 0; rt < RT; ++rt)
        #pragma unroll
        for (int r = 0; r < 4; ++r) {
            float p1 = 0.f, p2 = 0.f;
            #pragma unroll
            for (int dt = 0; dt < 4; ++dt) {
                p1 += acc[rt][dt][r] * a1v[dt];
                p2 += acc[rt][dt][r] * a2v[dt];
            }
            #pragma unroll
            for (int off = 1; off < 16; off <<= 1) {
                p1 += __shfl_xor(p1, off);
                p2 += __shfl_xor(p2, off);
            }
            if (c == 0) {
                int i = i0 + rt * 16 + g * 4 + r;
                s1[(size_t)h * N + i] = p1;
                s2[(size_t)h * N + i] = p2;
            }
        }
}

// ---------------------------------------------------------------- attn (r8-proven, verbatim)
template <int RT, int MODE>
__device__ void phase_attn(const u64* __restrict__ bits,
                           const float* __restrict__ s1h, const float* __restrict__ s2h,
                           const short* __restrict__ Htb,
                           short* __restrict__ outB, float* __restrict__ outF,
                           float* __restrict__ psum,
                           int h, int i0, int z, int zchunks, float* smem) {
    const int t = threadIdx.x, wave = t >> 6, lane = t & 63;
    const int c = lane & 15, g = lane >> 4;
    const int ROWS = RT * 16;
    float* redC  = smem;               // [2][ROWS][66]
    float* redS  = smem + 4224;        // [2][32] (ROWS-strided)
    float* emaxL = smem + 4288;        // [32]
    const float* s1 = s1h + (size_t)h * N;

    for (int r = wave; r < ROWS; r += 4) {
        int i = i0 + r;
        u64 word = bits[(size_t)i * NW + (lane >> 1)];
        unsigned hw = (lane & 1) ? (unsigned)(word >> 32) : (unsigned)word;
        int jj = lane * 32;
        float mx = -3e38f;
        #pragma unroll
        for (int q = 0; q < 8; ++q) {
            float4 v = *(const float4*)(s1 + jj + q * 4);
            if ((hw >> (q * 4 + 0)) & 1) mx = fmaxf(mx, v.x);
            if ((hw >> (q * 4 + 1)) & 1) mx = fmaxf(mx, v.y);
            if ((hw >> (q * 4 + 2)) & 1) mx = fmaxf(mx, v.z);
            if ((hw >> (q * 4 + 3)) & 1) mx = fmaxf(mx, v.w);
        }
        #pragma unroll
        for (int off = 32; off; off >>= 1) mx = fmaxf(mx, __shfl_xor(mx, off));
        if (lane == 0) {
            float e = mx + s2h[(size_t)h * N + i];
            emaxL[r] = fmaxf(e, ALPHA * e);
        }
    }
    __syncthreads();

    const u64* brow[RT];
    float s2v[RT], emv[RT];
    #pragma unroll
    for (int rt = 0; rt < RT; ++rt) {
        int i = i0 + rt * 16 + c;
        brow[rt] = bits + (size_t)i * NW;
        s2v[rt] = s2h[(size_t)h * N + i];
        emv[rt] = emaxL[rt * 16 + c];
    }

    f32x4 acc[RT][4];
    #pragma unroll
    for (int rt = 0; rt < RT; ++rt)
        #pragma unroll
        for (int dt = 0; dt < 4; ++dt) { acc[rt][dt][0]=0.f; acc[rt][dt][1]=0.f; acc[rt][dt][2]=0.f; acc[rt][dt][3]=0.f; }
    float wsum[RT];
    #pragma unroll
    for (int rt = 0; rt < RT; ++rt) wsum[rt] = 0.f;

    for (int cc = wave; cc < zchunks; cc += 4) {
        const int j0 = (z * zchunks + cc) * 32;
        const int wi = j0 >> 6;
        const int sh = (j0 & 32) + g * 8;
        const float4 q0 = *(const float4*)(s1 + j0 + g * 8);
        const float4 q1 = *(const float4*)(s1 + j0 + g * 8 + 4);
        const float s1e[8] = {q0.x, q0.y, q0.z, q0.w, q1.x, q1.y, q1.z, q1.w};
        bf16x8 af[RT];
        #pragma unroll
        for (int rt = 0; rt < RT; ++rt) {
            unsigned byte = (unsigned)(brow[rt][wi] >> sh) & 0xffu;
            #pragma unroll
            for (int e = 0; e < 8; ++e) {
                float ev = s1e[e] + s2v[rt];
                ev = fmaxf(ev, ALPHA * ev);                       // LeakyReLU
                float w = ((byte >> e) & 1u) ? __expf(ev - emv[rt]) : 0.f;
                wsum[rt] += w;
                af[rt][e] = f2bf(w);
            }
        }
        #pragma unroll
        for (int dt = 0; dt < 4; ++dt) {
            bf16x8 bf = *(const bf16x8*)(Htb + (size_t)(h * 64 + dt * 16 + c) * N + j0 + g * 8);
            #pragma unroll
            for (int rt = 0; rt < RT; ++rt)
                acc[rt][dt] = __builtin_amdgcn_mfma_f32_16x16x32_bf16(af[rt], bf, acc[rt][dt], 0, 0, 0);
        }
    }

    #pragma unroll
    for (int rt = 0; rt < RT; ++rt) {
        wsum[rt] += __shfl_xor(wsum[rt], 16);
        wsum[rt] += __shfl_xor(wsum[rt], 32);
    }

    if (wave >= 2) {
        int hf = wave - 2;
        #pragma unroll
        for (int rt = 0; rt < RT; ++rt) {
            #pragma unroll
            for (int dt = 0; dt < 4; ++dt)
                #pragma unroll
                for (int r = 0; r < 4; ++r)
                    redC[(size_t)hf * ROWS * 66 + (rt * 16 + g * 4 + r) * 66 + dt * 16 + c] = acc[rt][dt][r];
            if (g == 0) redS[hf * ROWS + rt * 16 + c] = wsum[rt];
        }
    }
    __syncthreads();
    if (wave < 2) {
        #pragma unroll
        for (int rt = 0; rt < RT; ++rt) {
            #pragma unroll
            for (int dt = 0; dt < 4; ++dt)
                #pragma unroll
                for (int r = 0; r < 4; ++r)
                    acc[rt][dt][r] += redC[(size_t)wave * ROWS * 66 + (rt * 16 + g * 4 + r) * 66 + dt * 16 + c];
            wsum[rt] += redS[wave * ROWS + rt * 16 + c];
        }
    }
    __syncthreads();
    if (wave == 1) {
        #pragma unroll
        for (int rt = 0; rt < RT; ++rt) {
            #pragma unroll
            for (int dt = 0; dt < 4; ++dt)
                #pragma unroll
                for (int r = 0; r < 4; ++r)
                    redC[(rt * 16 + g * 4 + r) * 66 + dt * 16 + c] = acc[rt][dt][r];
            if (g == 0) redS[rt * 16 + c] = wsum[rt];
        }
    }
    __syncthreads();
    if (wave == 0) {
        #pragma unroll
        for (int rt = 0; rt < RT; ++rt) {
            #pragma unroll
            for (int dt = 0; dt < 4; ++dt)
                #pragma unroll
                for (int r = 0; r < 4; ++r)
                    acc[rt][dt][r] += redC[(rt * 16 + g * 4 + r) * 66 + dt * 16 + c];
            wsum[rt] += redS[rt * 16 + c];
        }
        #pragma unroll
        for (int rt = 0; rt < RT; ++rt)
            #pragma unroll
            for (int r = 0; r < 4; ++r) {
                float ws = __shfl(wsum[rt], g * 4 + r);
                int row = rt * 16 + g * 4 + r;
                #pragma unroll
                for (int dt = 0; dt < 4; ++dt) {
                    if (MODE == 0) {
                        float v = acc[rt][dt][r] / ws;
                        v = v > 0.f ? v : (__expf(v) - 1.f);      // fused elu
                        outB[(size_t)(i0 + row) * (NHEADS * 64) + h * 64 + dt * 16 + c] = f2bf(v);
                    } else {
                        outF[((size_t)z * N + i0 + row) * 64 + dt * 16 + c] = acc[rt][dt][r];
                    }
                }
            }
        if (MODE == 1 && g == 0) {
            #pragma unroll
            for (int rt = 0; rt < RT; ++rt)
                psum[(size_t)z * N + i0 + rt * 16 + c] = wsum[rt];
        }
    }
}

// ---------------------------------------------------------------- the mega kernel (6 phases, 5 barriers)
__global__ __launch_bounds__(256, 2) void mega(MegaParams P) {
    __shared__ float smem[SMEM_FLOATS];
    const int bid = blockIdx.x;

    phase_prep(P, smem);
    gsync(P.bar + 0 * BAR_STRIDE);
    if ((bid & 3) == 0)     // 128 virtual blocks spread across CUs
        phase_gemm<2>(P.xb, P.Wtb, P.Htb, P.a1, P.a2, P.s1, P.s2, N, 512, 16, bid >> 2);
    gsync(P.bar + 1 * BAR_STRIDE);
    // layer-1 attn: 64 i-tiles x 8 heads = 512 blocks, 32 rows each
    phase_attn<2, 0>(P.bits, P.s1, P.s2, P.Htb, P.x2b, nullptr, nullptr,
                     bid >> 6, (bid & 63) * 32, 0, 64, smem);
    gsync(P.bar + 2 * BAR_STRIDE);
    if ((bid & 31) == 0)    // 16 virtual blocks
        phase_gemm<2>(P.x2b, P.Wftb, P.H2tb, P.a1f, P.a2f, P.s1f, P.s2f, N, 512, 16, bid >> 5);
    gsync(P.bar + 3 * BAR_STRIDE);
    // layer-2 attn: 128 i-tiles x 4 z = 512 blocks, 16 rows, unnormalized partials
    phase_attn<1, 1>(P.bits, P.s1f, P.s2f, P.H2tb, nullptr, P.pout, P.psum,
                     0, (bid >> 2) * 16, bid & 3, 16, smem);
    gsync(P.bar + 4 * BAR_STRIDE);
    {   // combine 4 z-partials
        int idx = bid * 256 + threadIdx.x;   // N*64 = 512*256
        int i = idx >> 6;
        float a = 0.f, s = 0.f;
        #pragma unroll
        for (int zz = 0; zz < 4; ++zz) {
            a += P.pout[(size_t)zz * N * 64 + idx];
            s += P.psum[(size_t)zz * N + i];
        }
        P.out[idx] = a / s;
    }
}

// ---------------------------------------------------------------- launch: memset(barriers) + 1 kernel
extern "C" void kernel_launch(void* const* d_in, const int* in_sizes, int n_in,
                              void* d_out, int out_size, void* d_ws, size_t ws_size,
                              hipStream_t stream) {
    char* ws = (char*)d_ws;
    MegaParams P;
    P.x   = (const float*)d_in[0];
    P.adj = (const int*)d_in[1];
    P.W   = (const float*)d_in[2];
    P.a1  = (const float*)d_in[3];
    P.a2  = (const float*)d_in[4];
    P.Wf  = (const float*)d_in[5];
    P.a1f = (const float*)d_in[6];
    P.a2f = (const float*)d_in[7];
    P.out = (float*)d_out;

    P.bar  = (unsigned*)ws; ws += 5 * BAR_STRIDE * 4;           // 20 KB barrier slots
    P.bits = (u64*)ws;   ws += (size_t)N * NW * 8;              // 512 KB
    P.xb   = (short*)ws; ws += (size_t)N * 512 * 2;             // 2 MB
    P.Wtb  = (short*)ws; ws += (size_t)8 * 64 * 512 * 2;        // 512 KB
    P.Wftb = (short*)ws; ws += (size_t)64 * 512 * 2;            // 64 KB
    P.Htb  = (short*)ws; ws += (size_t)512 * N * 2;             // 2 MB
    P.x2b  = (short*)ws; ws += (size_t)N * 512 * 2;             // 2 MB
    P.H2tb = (short*)ws; ws += (size_t)64 * N * 2;              // 256 KB
    P.s1   = (float*)ws; ws += (size_t)NHEADS * N * 4;
    P.s2   = (float*)ws; ws += (size_t)NHEADS * N * 4;
    P.s1f  = (float*)ws; ws += (size_t)N * 4;
    P.s2f  = (float*)ws; ws += (size_t)N * 4;
    P.pout = (float*)ws; ws += (size_t)4 * N * 64 * 4;          // 2 MB
    P.psum = (float*)ws; ws += (size_t)4 * N * 4;

    (void)hipMemsetAsync(P.bar, 0, 5 * BAR_STRIDE * 4, stream); // zero barrier slots (capturable)
    mega<<<dim3(NB), dim3(256), 0, stream>>>(P);
}